// Round 2
// baseline (112.888 us; speedup 1.0000x reference)
//
#include <hip/hip_runtime.h>

// Deformable conv (K=3, stride=1, pad=1, dil=1), N=8, Cin=Cout=128, H=W=64.
// R2: weights frag-major in global (L1-served, no LDS staging), 256-thr blocks,
//     grid=1024 (block = 32 wo x 128 cout), ping-pong samp LDS, 1 barrier/kk.
// ws: xt (NHWC bf16) 8 MB at +0 ; wtf (frag-major bf16) 288 KB at +8388608.

#define H  64
#define W  64
#define CIN 128
#define COUT 128
#define NB 8
#define KK 9

typedef short bf16x8 __attribute__((ext_vector_type(8)));
typedef float f32x4  __attribute__((ext_vector_type(4)));

__device__ __forceinline__ unsigned short f2bf(float f) {
    unsigned u = __builtin_bit_cast(unsigned, f);
    u += 0x7FFFu + ((u >> 16) & 1u);          // round-nearest-even
    return (unsigned short)(u >> 16);
}
__device__ __forceinline__ float lo_f(unsigned u) { return __builtin_bit_cast(float, u << 16); }
__device__ __forceinline__ float hi_f(unsigned u) { return __builtin_bit_cast(float, u & 0xFFFF0000u); }

// w[co][c][kk] fp32 -> wtf frag-major: [kk][nt:8][ct:4][lane:64][j:8] bf16.
// B-frag (verified R1): co = 16*nt + (lane&15), c = 32*ct + 8*(lane>>4) + j.
__global__ void prep_weight(const float* __restrict__ w, unsigned short* __restrict__ wtf) {
    int id = blockIdx.x * 256 + threadIdx.x;     // 18432 threads
    int lane = id & 63;
    int ct = (id >> 6) & 3;
    int nt = (id >> 8) & 7;
    int kk = id >> 11;
    if (kk >= KK) return;
    int co = nt * 16 + (lane & 15);
    int c0 = ct * 32 + (lane >> 4) * 8;
    unsigned short v[8];
    #pragma unroll
    for (int j = 0; j < 8; ++j)
        v[j] = f2bf(w[((size_t)co * CIN + c0 + j) * KK + kk]);
    *(uint4*)(wtf + (size_t)id * 8) = *(const uint4*)v;
}

// x[n][c][y][x] fp32 -> xt[n][y][x][c] bf16. One (n,y) row per block.
__global__ void prep_x(const float* __restrict__ x, unsigned short* __restrict__ xt) {
    __shared__ float tile[CIN][W + 1];
    int b = blockIdx.x;                 // n*64 + y
    int n = b >> 6, y = b & 63;
    int t = threadIdx.x;
    int l = t & 63, g = t >> 6;
    const float* src = x + ((size_t)n * CIN * H + y) * W;
    #pragma unroll
    for (int i = 0; i < 32; ++i) {
        int c = g * 32 + i;
        tile[c][l] = src[(size_t)c * H * W + l];   // coalesced 256B row per wave
    }
    __syncthreads();
    int xp = t & 63;                    // lane-major x => conflict-free LDS reads
    int cb = (t >> 6) * 32;
    unsigned short* dst = xt + (((size_t)(n * H + y) * W + xp) * CIN + cb);
    unsigned rr[16];
    #pragma unroll
    for (int i = 0; i < 16; ++i) {
        rr[i] = (unsigned)f2bf(tile[cb + 2 * i][xp])
              | ((unsigned)f2bf(tile[cb + 2 * i + 1][xp]) << 16);
    }
    #pragma unroll
    for (int i = 0; i < 4; ++i)
        ((uint4*)dst)[i] = make_uint4(rr[4*i], rr[4*i+1], rr[4*i+2], rr[4*i+3]);
}

// Block = (n, ho, half): 32 wo x 128 cout. 256 threads = 4 waves.
// Wave wv: m-tile (wv&1) (16 wo), nt group (wv>>1) (4 cout-tiles of 16).
__global__ __launch_bounds__(256, 4) void deform_main(
        const float* __restrict__ offs, const unsigned short* __restrict__ xt,
        const unsigned short* __restrict__ wtf, float* __restrict__ out) {
    __shared__ __attribute__((aligned(16))) unsigned short samp[2][32][CIN + 8];

    int b  = blockIdx.x;                 // ((n*64 + ho)<<1) | half
    int hh = b & 1;
    int ho = (b >> 1) & 63;
    int n  = b >> 7;
    int t = threadIdx.x;
    int lane = t & 63, wv = t >> 6;
    int lm = lane & 15, lq = lane >> 4;

    // sampling role: local pos pl (0..31), 16-channel chunk cb
    int pl = t >> 3;
    int cb = (t & 7) << 4;
    int wo_s = (hh << 5) + pl;           // global wo this thread samples

    const float* offp = offs + (((size_t)n * 2 * KK) * H + ho) * W + wo_s;
    const unsigned short* xbase = xt + (size_t)n * H * W * CIN + cb;

    f32x4 acc[4] = {{0,0,0,0},{0,0,0,0},{0,0,0,0},{0,0,0,0}};

    float dy = offp[0];
    float dx = offp[(size_t)H * W];
    int kh = 0, kw = 0;
    for (int kk = 0; kk < KK; ++kk) {
        // ---- bilinear-sample 16 channels at (ho,wo_s,kk) into samp[kk&1] ----
        float py = (float)(ho - 1 + kh) + dy;
        float px = (float)(wo_s - 1 + kw) + dx;
        float y0f = floorf(py), x0f = floorf(px);
        float wy1 = py - y0f, wx1 = px - x0f;
        float wy0 = 1.f - wy1, wx0 = 1.f - wx1;
        int y0 = (int)y0f, x0 = (int)x0f;
        int y1 = y0 + 1, x1 = x0 + 1;
        bool vy0 = (unsigned)y0 < (unsigned)H, vy1 = (unsigned)y1 < (unsigned)H;
        bool vx0 = (unsigned)x0 < (unsigned)W, vx1 = (unsigned)x1 < (unsigned)W;
        float w00 = (vy0 && vx0) ? wy0 * wx0 : 0.f;
        float w01 = (vy0 && vx1) ? wy0 * wx1 : 0.f;
        float w10 = (vy1 && vx0) ? wy1 * wx0 : 0.f;
        float w11 = (vy1 && vx1) ? wy1 * wx1 : 0.f;
        int yc0 = min(max(y0, 0), H - 1), yc1 = min(max(y1, 0), H - 1);
        int xc0 = min(max(x0, 0), W - 1), xc1 = min(max(x1, 0), W - 1);
        const unsigned short* r0 = xbase + (size_t)yc0 * (W * CIN);
        const unsigned short* r1 = xbase + (size_t)yc1 * (W * CIN);
        const unsigned short* b00 = r0 + (xc0 << 7);
        const unsigned short* b01 = r0 + (xc1 << 7);
        const unsigned short* b10 = r1 + (xc0 << 7);
        const unsigned short* b11 = r1 + (xc1 << 7);
        unsigned short* dst = &samp[kk & 1][pl][cb];
        #pragma unroll
        for (int j = 0; j < 2; ++j) {
            uint4 q00 = *(const uint4*)(b00 + 8 * j);
            uint4 q01 = *(const uint4*)(b01 + 8 * j);
            uint4 q10 = *(const uint4*)(b10 + 8 * j);
            uint4 q11 = *(const uint4*)(b11 + 8 * j);
            const unsigned* a0 = (const unsigned*)&q00;
            const unsigned* a1 = (const unsigned*)&q01;
            const unsigned* a2 = (const unsigned*)&q10;
            const unsigned* a3 = (const unsigned*)&q11;
            unsigned rr[4];
            #pragma unroll
            for (int i = 0; i < 4; ++i) {
                float v0 = w00*lo_f(a0[i]) + w01*lo_f(a1[i]) + w10*lo_f(a2[i]) + w11*lo_f(a3[i]);
                float v1 = w00*hi_f(a0[i]) + w01*hi_f(a1[i]) + w10*hi_f(a2[i]) + w11*hi_f(a3[i]);
                rr[i] = (unsigned)f2bf(v0) | ((unsigned)f2bf(v1) << 16);
            }
            *(uint4*)(dst + 8 * j) = make_uint4(rr[0], rr[1], rr[2], rr[3]);
        }
        // prefetch next kk's offsets BEFORE the barrier (overlaps MFMA below)
        if (kk < KK - 1) {
            dy = offp[(size_t)(2 * kk + 2) * H * W];
            dx = offp[(size_t)(2 * kk + 3) * H * W];
        }
        ++kw; if (kw == 3) { kw = 0; ++kh; }
        __syncthreads();
        // ---- MFMA: A from LDS, B-frags straight from global (L1-resident) ----
        const unsigned short* arow = &samp[kk & 1][((wv & 1) << 4) + lm][lq << 3];
        const unsigned short* wk = wtf + (size_t)kk * 16384
                                       + ((size_t)(wv >> 1) << 4) * 512 + (lane << 3);
        #pragma unroll
        for (int ct = 0; ct < 4; ++ct) {
            bf16x8 a = *(const bf16x8*)(arow + (ct << 5));
            #pragma unroll
            for (int i = 0; i < 4; ++i) {
                bf16x8 bf = *(const bf16x8*)(wk + ((i << 2) + ct) * 512);
                acc[i] = __builtin_amdgcn_mfma_f32_16x16x32_bf16(a, bf, acc[i], 0, 0, 0);
            }
        }
        // ping-pong buffer => no second barrier needed
    }
    // epilogue: D row = 4*lq + r -> wo, col = lm -> co ; float4 over wo
    int wo = (hh << 5) + ((wv & 1) << 4) + (lq << 2);
    #pragma unroll
    for (int i = 0; i < 4; ++i) {
        int co = ((wv >> 1) << 6) + (i << 4) + lm;
        *(f32x4*)(out + (((size_t)(n * COUT + co) * H + ho) * W + wo)) = acc[i];
    }
}

extern "C" void kernel_launch(void* const* d_in, const int* in_sizes, int n_in,
                              void* d_out, int out_size, void* d_ws, size_t ws_size,
                              hipStream_t stream) {
    const float* x      = (const float*)d_in[0];   // (8,128,64,64)
    const float* offset = (const float*)d_in[1];   // (8,18,64,64)
    const float* weight = (const float*)d_in[2];   // (128,128,3,3)
    float* out = (float*)d_out;

    unsigned short* xt  = (unsigned short*)d_ws;                                  // 8 MB
    unsigned short* wtf = (unsigned short*)((char*)d_ws + (size_t)NB*H*W*CIN*2);  // 288 KB

    hipLaunchKernelGGL(prep_weight, dim3(72), dim3(256), 0, stream, weight, wtf);
    hipLaunchKernelGGL(prep_x, dim3(NB * H), dim3(256), 0, stream, x, xt);
    hipLaunchKernelGGL(deform_main, dim3(NB * H * 2), dim3(256), 0, stream,
                       offset, xt, wtf, out);
}